// Round 6
// baseline (311.844 us; speedup 1.0000x reference)
//
#include <hip/hip_runtime.h>
#include <stdint.h>

// out[b,o,m] = sum_i in[b,i,m] * w[i,o,m]  (complex, fp32)
// B=32, Ci=Co=128, M=64*65=4160. One float2 per complex element.
//
// R6: 128B DRAM granules. Block = 32b x 64o x 16 modes (o-half), 1024 thr,
// grid 520 (= 8 XCD x 65; o-half pairs adjacent per XCD -> I L2-reuse).
// Per (row,k) the DMA reads 16 modes * 8B = 128B contiguous (R5's 64B runs
// capped effective HBM at ~3.2 TB/s -- DRAM row-activation bound).
// Thread tile 4b x 8o (64-reg acc; ~115 total -> 16 waves/CU, 1 blk/CU).
// DMA: global_load_lds dwordx4, double-buffered 2 x 48KB, counted vmcnt
// (uniform 3 loads/thread/chunk, never 0 in main loop).
// Linear LDS, no swizzle: 128B rows cover all 32 banks exactly ->
// W-read at the 4-cycle b64 floor, A-read is broadcast.

typedef float f2 __attribute__((ext_vector_type(2)));

#define NB 32
#define CI 128
#define CO 128
#define OT 64
#define MODES 4160
#define MPB 16
#define KC 4
#define NCHUNK (CI / KC)               // 32
#define ABUF_F2 (KC * NB * MPB)        // 2048 f2 = 16 KB
#define WBUF_F2 (KC * OT * MPB)        // 4096 f2 = 32 KB
#define BUF_F2  (ABUF_F2 + WBUF_F2)    // 48 KB per buffer

// acc.lo += a.lo*w.lo - a.hi*w.hi ; acc.hi += a.lo*w.hi + a.hi*w.lo
#define CFMA(acc, av, wv)                                                      \
  asm("v_pk_fma_f32 %0, %1, %2, %0 op_sel:[0,0,0] op_sel_hi:[0,1,1]"           \
      : "+v"(acc) : "v"(av), "v"(wv));                                         \
  asm("v_pk_fma_f32 %0, %1, %2, %0 op_sel:[1,1,0] op_sel_hi:[1,0,1] "          \
      "neg_lo:[1,0,0]"                                                         \
      : "+v"(acc) : "v"(av), "v"(wv));

#define VM_WAIT(N) asm volatile("s_waitcnt vmcnt(" #N ")" ::: "memory")

__device__ __forceinline__ void gload16(const f2* g, f2* l) {
    __builtin_amdgcn_global_load_lds(
        (const __attribute__((address_space(1))) uint32_t*)g,
        (__attribute__((address_space(3))) uint32_t*)l, 16, 0, 0);
}

// Stage one K-chunk (KC=4) into dst. 3 x 16B DMA per thread (uniform).
// A (1024 units): u = t  <-> kk=u>>8, b=(u>>3)&31, mlq=u&7. LDS f2 = u*2.
// W (2048 units): j = p*1024+t <-> kk=j>>9, o=(j>>3)&63, mlq=j&7.
//   LDS f2 = ABUF + j*2 = ABUF + kk*1024 + o*16 + ml.  All linear.
__device__ __forceinline__ void stage_chunk(const f2* __restrict__ Ig,
                                            const f2* __restrict__ Wl,
                                            f2* dst, int t, int m0,
                                            int obase, int k0) {
    {
        const int kk = t >> 8, b = (t >> 3) & 31, ml0 = (t & 7) << 1;
        gload16(Ig + (size_t)(b * CI + k0 + kk) * MODES + m0 + ml0,
                dst + t * 2);
    }
#pragma unroll
    for (int p = 0; p < 2; ++p) {
        const int j  = p * 1024 + t;
        const int kk = j >> 9, o = (j >> 3) & 63, ml0 = (j & 7) << 1;
        gload16(Wl + (size_t)((k0 + kk) * CO + obase + o) * MODES + m0 + ml0,
                dst + ABUF_F2 + j * 2);
    }
}

__global__ __launch_bounds__(1024, 4)
void cmul2d_kernel(const f2* __restrict__ Ig,
                   const f2* __restrict__ Wl,
                   f2* __restrict__ Og) {
    __shared__ f2 lds[2 * BUF_F2];   // 96 KB -> 1 block/CU

    const int t = threadIdx.x;

    // XCD-chunked job map (520 = 8 XCDs x 65). jid pairs (2k,2k+1) = the two
    // o-halves of one mode-16-group -> adjacent in one XCD -> I L2-reuse.
    const int bid   = blockIdx.x;
    const int jid   = (bid & 7) * 65 + (bid >> 3);
    const int m0    = (jid >> 1) * MPB;
    const int obase = (jid & 1) * OT;

    const int ml = t & 15;     // mode lane (128B-coalesced epilogue)
    const int s  = t >> 4;     // worker 0..63
    const int so = s & 7;      // o-group (8 o each)
    const int sb = s >> 3;     // b-group (4 b each) -- wave-uniform

    f2 acc[4][8];
#pragma unroll
    for (int r = 0; r < 4; ++r)
#pragma unroll
        for (int q = 0; q < 8; ++q) acc[r][q] = (f2)(0.0f);

    // prologue: fill both pipeline stages (6 loads in flight / thread)
    stage_chunk(Ig, Wl, lds,          t, m0, obase, 0);
    stage_chunk(Ig, Wl, lds + BUF_F2, t, m0, obase, KC);

#pragma unroll 1
    for (int c = 0; c < NCHUNK; ++c) {
        // wait only for chunk c's 3 loads; chunk c+1 stays in flight
        if (c < NCHUNK - 1) { VM_WAIT(3); } else { VM_WAIT(0); }
        __builtin_amdgcn_s_barrier();        // chunk c landed for all waves
        __builtin_amdgcn_sched_barrier(0);

        const f2* Ab = lds + (c & 1) * BUF_F2;
        const f2* Wb = Ab + ABUF_F2;
#pragma unroll
        for (int kk = 0; kk < KC; ++kk) {
            f2 a[4], w[8];
#pragma unroll
            for (int r = 0; r < 4; ++r)          // broadcast across 4 workers
                a[r] = Ab[kk * (NB * MPB) + (sb * 4 + r) * MPB + ml];
#pragma unroll
            for (int q = 0; q < 8; ++q)          // 4 x 128B runs = bank floor
                w[q] = Wb[kk * (OT * MPB) + (so * 8 + q) * MPB + ml];
#pragma unroll
            for (int r = 0; r < 4; ++r)
#pragma unroll
                for (int q = 0; q < 8; ++q) {
                    CFMA(acc[r][q], a[r], w[q]);
                }
        }

        __builtin_amdgcn_sched_barrier(0);
        __builtin_amdgcn_s_barrier();        // all waves done reading buf c&1
        if (c + 2 < NCHUNK)                  // refill just-freed buffer
            stage_chunk(Ig, Wl, lds + (c & 1) * BUF_F2, t, m0, obase,
                        (c + 2) * KC);
    }

    // epilogue: per (b,o) the 16 ml lanes are consecutive -> 128B stores
#pragma unroll
    for (int r = 0; r < 4; ++r) {
        const int b = sb * 4 + r;
#pragma unroll
        for (int q = 0; q < 8; ++q) {
            const int o = obase + so * 8 + q;
            Og[(size_t)(b * CO + o) * MODES + m0 + ml] = acc[r][q];
        }
    }
}

extern "C" void kernel_launch(void* const* d_in, const int* in_sizes, int n_in,
                              void* d_out, int out_size, void* d_ws, size_t ws_size,
                              hipStream_t stream) {
    const f2* I = (const f2*)d_in[0];
    const f2* W = (const f2*)d_in[1];
    f2* O = (f2*)d_out;
    dim3 grid(520);    // 260 mode-16-groups x 2 o-halves
    dim3 block(1024);
    cmul2d_kernel<<<grid, block, 0, stream>>>(I, W, O);
}